// Round 21
// baseline (56.676 us; speedup 1.0000x reference)
//
#include <hip/hip_runtime.h>
#include <cmath>

#define BB 4
#define TT 8192
#define DD 1024
#define DBLK 16              // d's per block (R16-proven geometry)
#define NDB (DD/DBLK)        // 64 d-blocks
#define NCHAIN (BB*NDB)      // 256 chains == 256 blocks == 1 per CU
#define CL 1024              // timesteps per chunk
#define NITER (TT/CL)        // 8 chunks, carry in registers
#define NTHR 1024            // 16 waves (R20: same perf as 8; more store issue par.)
#define NPART (NTHR/DBLK)    // 64 t-parts
#define PLEN (CL/NPART)      // 16 steps per part
#define NGRP 8               // stitch groups (8 parts each)

typedef float fvec4 __attribute__((ext_vector_type(4)));

// y[b,t,d] = Re(h[t]),  h[t] = r*h[t-1] + x[t],  r = exp(-|a_d|) * cis(w_d)
//
// R21 = R20 + WIDE STORES. R16/R19/R20 plateau at ~50.8us = 84% of the
// float4-copy ceiling (6.29 TB/s); the one remaining structural difference
// from that bench is scalar 4B/lane y-stores (4 disjoint 64B granules,
// 4KB apart, per store-inst). Fix: the scanned tile is dead after the scan
// -> finish writes results into tile[cur] (linear, per-wave-private rows),
// then each wave streams its region with fvec4 nontemporal stores
// (1KB/wave-inst, full 128B lines == the copy-bench shape). Finish-write /
// wide-read / next-stage-write all hit the SAME per-wave LDS region, so
// intra-wave lgkmcnt ordering suffices -- no extra barrier.
// Carried over: persistent chains, register carry, no lookback/flags,
// FIFO-counted vmcnt (4/8/4, never 0 mid-loop), XCD-pairing chain swizzle,
// both-sides XOR bank swizzle on the x path.

__global__ __launch_bounds__(NTHR, 1) void fftconv_persist(
    const float* __restrict__ x, const float* __restrict__ decay,
    const float* __restrict__ freq, float* __restrict__ y)
{
    __shared__ float  tile[2][CL*DBLK];    // 128 KB (double buffer)
    __shared__ float2 Ssub[NPART][DBLK];   // 8 KB  per-part sub-aggregates
    __shared__ float2 eoff[NPART][DBLK];   // 8 KB  within-group exclusive offsets
    __shared__ float2 Gs[NGRP][DBLK];      // 1 KB  group aggregates
    __shared__ float2 Eg[NGRP][DBLK];      // 1 KB  group-exclusive state (incl. carry)

    const int tid  = threadIdx.x;
    const int l16  = tid & 15;             // d-lane
    const int part = tid >> 4;             // 0..63 (t-part)
    const int wv   = tid >> 6;             // wave 0..15
    const int wl   = tid & 63;             // lane in wave
    const int bid  = blockIdx.x;
    // XCD-pairing swizzle (R16-proven): 32 contiguous chains per XCD
    const int chain = (bid & 7)*32 + (bid >> 3);
    const int dblk  = chain & (NDB-1);
    const int b     = chain >> 6;          // NDB=64
    const int d     = dblk*DBLK + l16;

    // per-d constants (once per block, reused for 8 chunks)
    const float a = fabsf(decay[d]);
    const float w = freq[d];
    float s_, c_, e;
    e = expf(-a);                     sincosf(w, &s_, &c_);
    const float rr = e*c_, ri = e*s_;                          // r
    e = expf(-a*(float)PLEN);         sincosf(w*(float)PLEN, &s_, &c_);
    const float Msr = e*c_, Msi = e*s_;                        // r^16  (part step)
    e = expf(-a*(float)(PLEN*NGRP));  sincosf(w*(float)(PLEN*NGRP), &s_, &c_);
    const float Mgr = e*c_, Mgi = e*s_;                        // r^128 (group step)
    {
        const float tj = (float)(PLEN*(part & (NGRP-1)));
        e = expf(-a*tj); sincosf(w*tj, &s_, &c_);
    }
    const float Mjr = e*c_, Mji = e*s_;                        // r^(16*(part%8))

    const float* xch = x + (size_t)b*TT*DD + dblk*DBLK;
    float*       ych = y + (size_t)b*TT*DD + dblk*DBLK;

    // stage chunk k into tile[buf]: 4 gload_lds x 16B per wave (16 waves).
    // LDS dest linear (HW rule); GLOBAL source pre-swizzled with the
    // involution u ^ (((u>>6)&1)<<2) <=> float f ^ (((f>>8)&1)<<4),
    // matching the scan's read-side XOR (both-sides-or-neither, rule #21).
    auto stage = [&](int k, int buf) {
        const float* xc = xch + (size_t)(k*CL)*DD;
#pragma unroll
        for (int i = 0; i < 4; ++i) {
            const int u0 = (wv*4 + i)*64;                  // physical 16B-unit base
            const int up = u0 + wl;
            const int ul = up ^ (((up >> 6) & 1) << 2);    // logical unit
            __builtin_amdgcn_global_load_lds(
                (const __attribute__((address_space(1))) void*)
                    (xc + (size_t)(ul >> 2)*DD + ((ul & 3) << 2)),
                (__attribute__((address_space(3))) void*)&tile[buf][u0 << 2],
                16, 0, 0);
        }
    };

    float Hr = 0.f, Hi = 0.f;              // chain carry (valid in tid<16)
    const int cxor = (part & 1) << 4;      // read-side swizzle (float idx)

    stage(0, 0);                           // prologue: iteration 0's tile

    for (int k = 0; k < NITER; ++k) {
        const int cur = k & 1;

        // ---- issue next stage first: loads fly during this scan ----
        if (k + 1 < NITER) stage(k + 1, cur ^ 1);

        // ---- FIFO-counted wait: stage(k)'s 4 loads retired ----
        // younger ops after stage(k): stores(k-1) 4 + stage(k+1) 4
        if (k == 0)             asm volatile("s_waitcnt vmcnt(4)" ::: "memory");
        else if (k + 1 < NITER) asm volatile("s_waitcnt vmcnt(8)" ::: "memory");
        else                    asm volatile("s_waitcnt vmcnt(4)" ::: "memory");
        __builtin_amdgcn_s_barrier();                  // tile[cur] ready (all waves)
        __builtin_amdgcn_sched_barrier(0);

        // ---- scan from zero; real-part history in registers ----
        float hRr[PLEN];
        {
            float hr = 0.f, hi = 0.f;
            const int fbase = part << 8;               // part*256 floats
#pragma unroll
            for (int t = 0; t < PLEN; ++t) {
                float xv = tile[cur][(fbase + (t << 4) + l16) ^ cxor];
                float nr = fmaf(rr, hr, fmaf(-ri, hi, xv));
                hi = fmaf(rr, hi, ri*hr);
                hr = nr;
                hRr[t] = hr;
            }
            Ssub[part][l16] = make_float2(hr, hi);
        }
        asm volatile("s_waitcnt lgkmcnt(0)" ::: "memory");
        __builtin_amdgcn_s_barrier();                  // B2: Ssub visible
        __builtin_amdgcn_sched_barrier(0);

        // ---- stitch level 1 (128 threads): within-group exclusive prefixes ----
        if (tid < NGRP*DBLK) {
            const int sp = tid >> 4;                   // group 0..7
            const int l  = tid & 15;
            float Wr = 0.f, Wi = 0.f;
#pragma unroll
            for (int j = 0; j < NGRP; ++j) {
                const int p = sp*NGRP + j;
                eoff[p][l] = make_float2(Wr, Wi);
                float2 Sp = Ssub[p][l];
                float nr = fmaf(Msr, Wr, fmaf(-Msi, Wi, Sp.x));
                Wi = fmaf(Msr, Wi, fmaf(Msi, Wr, Sp.y));
                Wr = nr;
            }
            Gs[sp][l] = make_float2(Wr, Wi);           // group aggregate
        }
        asm volatile("s_waitcnt lgkmcnt(0)" ::: "memory");
        __builtin_amdgcn_s_barrier();                  // B2b: eoff/Gs visible
        __builtin_amdgcn_sched_barrier(0);

        // ---- stitch level 2 (16 lanes): group scan, carry absorbed ----
        if (tid < DBLK) {
            float Er = Hr, Ei = Hi;                    // E init = carry INTO chunk
#pragma unroll
            for (int g = 0; g < NGRP; ++g) {
                Eg[g][l16] = make_float2(Er, Ei);
                float2 G = Gs[g][l16];
                float nr = fmaf(Mgr, Er, fmaf(-Mgi, Ei, G.x));
                Ei = fmaf(Mgr, Ei, fmaf(Mgi, Er, G.y));
                Er = nr;
            }
            Hr = Er; Hi = Ei;                          // carry OUT of chunk
        }
        asm volatile("s_waitcnt lgkmcnt(0)" ::: "memory");
        __builtin_amdgcn_s_barrier();                  // B3: Eg visible
        __builtin_amdgcn_sched_barrier(0);

        // ---- finish: write y values into tile[cur] (dead buffer, LINEAR) ----
        {
            const int g = part >> 3;
            float2 eo = eoff[part][l16];
            float2 Ev = Eg[g][l16];
            float Sr = eo.x + (Mjr*Ev.x - Mji*Ev.y);
            float Si = eo.y + (Mjr*Ev.y + Mji*Ev.x);
            float wr = rr*Sr - ri*Si;      // w = r * S
            float wi = rr*Si + ri*Sr;
            const int fbase = part << 8;   // rows part*16.. : wave-private region
#pragma unroll
            for (int t = 0; t < PLEN; ++t) {
                tile[cur][fbase + (t << 4) + l16] = hRr[t] + wr;
                float nwr = rr*wr - ri*wi; // w *= r
                wi = rr*wi + ri*wr;
                wr = nwr;
            }
        }

        // ---- wide store: each wave streams ITS OWN region (same rows it
        //      just finish-wrote; same rows its next stage overwrites) ----
        {
            float* yck = ych + (size_t)(k*CL)*DD;
            const float* lb = &tile[cur][0];
#pragma unroll
            for (int i = 0; i < 4; ++i) {
                const int u  = (wv*4 + i)*64 + wl;     // 16B unit
                const int rt = u >> 2;                 // row (timestep in chunk)
                const int dc = (u & 3) << 2;           // col base
                fvec4 v = *reinterpret_cast<const fvec4*>(lb + (u << 2));
                __builtin_nontemporal_store(
                    v, reinterpret_cast<fvec4*>(yck + (size_t)rt*DD + dc));
            }
        }
        // no trailing wait: stores drain under the next iteration's scan
    }
}

extern "C" void kernel_launch(void* const* d_in, const int* in_sizes, int n_in,
                              void* d_out, int out_size, void* d_ws, size_t ws_size,
                              hipStream_t stream) {
    const float* x     = (const float*)d_in[0];
    const float* decay = (const float*)d_in[1];
    const float* freq  = (const float*)d_in[2];
    float*       y     = (float*)d_out;

    // single dispatch; no workspace, no flags, no memset
    fftconv_persist<<<NCHAIN, NTHR, 0, stream>>>(x, decay, freq, y);
}

// Round 22
// 50.841 us; speedup vs baseline: 1.1148x; 1.1148x over previous
//
#include <hip/hip_runtime.h>
#include <cmath>

#define BB 4
#define TT 8192
#define DD 1024
#define DBLK 16              // d's per block (chain width)
#define NDB (DD/DBLK)        // 64 d-blocks
#define NCHAIN (BB*NDB)      // 256 chains == 256 blocks == 1 per CU
#define CL 1024              // timesteps per chunk
#define NITER (TT/CL)        // 8 chunks, carry in registers
#define NTHR 512             // 8 waves
#define NPART (NTHR/DBLK)    // 32 t-parts
#define PLEN (CL/NPART)      // 32 steps per part

// y[b,t,d] = Re(h[t]),  h[t] = r*h[t-1] + x[t],  r = exp(-|a_d|) * cis(w_d)
//
// R22 == R16 verbatim (best: 50.71 us). Final configuration after the
// R1-R21 search. Why this shape:
//  - persistent chains, carry in registers: no lookback/flags/memset
//    (cross-block sync variants all plateau 67-73us: R7/R9/R15)
//  - DBLK=16: 64B store granules merge to exact 131MB WRITE via L2
//    (DBLK=8 amplifies writes, R17; nt stores break merging, R21)
//  - CL=1024, NITER=8: fewest serial stitch/barrier generations (R18)
//  - counted s_waitcnt vmcnt (never 0 mid-loop) + raw s_barrier:
//    stage loads overlap finish stores (R16 vs R15: 67->51us)
//  - 1 block/CU, 8 waves: occupancy/TLP increases are neutral (R17/R20)
//  - scan 4-way LDS conflicts are benign (R19: removing them = 0 gain)
// Logical traffic 268MB @ 50.7us = 5.29 TB/s = 84% of the float4-copy
// ceiling (6.29 TB/s) with a dependent-scan + 4 barriers/chunk inside.

__global__ __launch_bounds__(NTHR, 2) void fftconv_persist(
    const float* __restrict__ x, const float* __restrict__ decay,
    const float* __restrict__ freq, float* __restrict__ y)
{
    __shared__ float  tile[2][CL*DBLK];    // 128 KB (double buffer)
    __shared__ float2 Ssub[NPART][DBLK];   // 4 KB  per-part sub-aggregates
    __shared__ float2 eoff[NPART][DBLK];   // 4 KB  exclusive in-chunk offsets
    __shared__ float2 HB[DBLK];            // 128 B carry broadcast

    const int tid  = threadIdx.x;
    const int l16  = tid & 15;             // d-lane
    const int part = tid >> 4;             // 0..31 (t-part)
    const int wv   = tid >> 6;             // wave 0..7
    const int wl   = tid & 63;             // lane in wave
    const int bid  = blockIdx.x;
    // XCD-pairing swizzle: 32 contiguous chains per XCD -> sibling 64B
    // store granules merge into full 128B lines in the shared per-XCD L2.
    const int chain = (bid & 7)*32 + (bid >> 3);
    const int dblk  = chain & (NDB-1);
    const int b     = chain >> 6;          // NDB=64
    const int d     = dblk*DBLK + l16;

    // per-d constants (computed ONCE per block, reused for 8 chunks)
    const float a = fabsf(decay[d]);
    const float w = freq[d];
    float s_, c_, e;
    e = expf(-a);                    sincosf(w, &s_, &c_);
    const float rr = e*c_, ri = e*s_;                         // r
    e = expf(-a*(float)PLEN);        sincosf(w*(float)PLEN, &s_, &c_);
    const float Msr = e*c_, Msi = e*s_;                       // r^32  (part step)
    e = expf(-a*(float)CL);          sincosf(w*(float)CL, &s_, &c_);
    const float Mcr = e*c_, Mci = e*s_;                       // r^1024 (chunk step)
    e = expf(-a*(float)(PLEN*part)); sincosf(w*(float)(PLEN*part), &s_, &c_);
    const float Mpr = e*c_, Mpi = e*s_;                       // r^(32*part)

    const float* xch = x + (size_t)b*TT*DD + dblk*DBLK;
    float*       ych = y + (size_t)b*TT*DD + dblk*DBLK;

    // stage chunk k into tile[buf]: 8 global_load_lds x 16B per wave.
    // LDS dest is wave-uniform base + lane*16 (HW rule) == rows r0..r0+15
    // of the [1024][16] tile; per-lane global src matches that layout.
    auto stage = [&](int k, int buf) {
        const float* xc = xch + (size_t)(k*CL)*DD;
        const int rofs = wl >> 2;
        const int gofs = (wl & 3) << 2;
#pragma unroll
        for (int i = 0; i < 8; ++i) {
            const int r0 = (wv*8 + i)*16;
            __builtin_amdgcn_global_load_lds(
                (const __attribute__((address_space(1))) void*)
                    (xc + (size_t)(r0 + rofs)*DD + gofs),
                (__attribute__((address_space(3))) void*)&tile[buf][r0*DBLK],
                16, 0, 0);
        }
    };

    float Hr = 0.f, Hi = 0.f;              // chain carry (lives in tid<16)

    stage(0, 0);                           // prologue
    asm volatile("s_waitcnt vmcnt(0)" ::: "memory");
    __builtin_amdgcn_s_barrier();
    __builtin_amdgcn_sched_barrier(0);

    for (int k = 0; k < NITER; ++k) {
        const int cur = k & 1;

        // ---- scan from zero; real-part history in registers ----
        float hRr[PLEN];
        {
            float hr = 0.f, hi = 0.f;
            const int rowbase = part*PLEN;
#pragma unroll
            for (int t = 0; t < PLEN; ++t) {
                float xv = tile[cur][(rowbase + t)*DBLK + l16];
                float nr = fmaf(rr, hr, fmaf(-ri, hi, xv));
                hi = fmaf(rr, hi, ri*hr);
                hr = nr;
                hRr[t] = hr;
            }
            Ssub[part][l16] = make_float2(hr, hi);
        }
        asm volatile("s_waitcnt lgkmcnt(0)" ::: "memory");
        __builtin_amdgcn_s_barrier();                    // B2: Ssub visible
        __builtin_amdgcn_sched_barrier(0);

        // ---- prefetch next chunk (reads fly under stitch+finish) ----
        if (k + 1 < NITER) stage(k + 1, cur ^ 1);

        // ---- stitch (16 lanes): exclusive offsets + carry update ----
        if (tid < DBLK) {
            float Lr = 0.f, Li = 0.f;
#pragma unroll
            for (int p = 0; p < NPART; ++p) {
                eoff[p][l16] = make_float2(Lr, Li);
                float2 Sp = Ssub[p][l16];
                float nr = fmaf(Msr, Lr, fmaf(-Msi, Li, Sp.x));
                Li = fmaf(Msr, Li, fmaf(Msi, Lr, Sp.y));
                Lr = nr;
            }
            HB[l16] = make_float2(Hr, Hi);  // carry INTO this chunk
            // H = A + Mc*H  (A = Lr,Li = zero-seeded chunk aggregate)
            float nHr = fmaf(Mcr, Hr, fmaf(-Mci, Hi, Lr));
            Hi = fmaf(Mcr, Hi, fmaf(Mci, Hr, Li));
            Hr = nHr;
        }
        asm volatile("s_waitcnt lgkmcnt(0)" ::: "memory");
        __builtin_amdgcn_s_barrier();                    // B3: eoff/HB visible
        __builtin_amdgcn_sched_barrier(0);

        // ---- finish: S = eoff + r^(32*part)*H_in; y[t] = hRr[t] + Re(r^(t+1) S) ----
        {
            float2 Hp = HB[l16];
            float2 eo = eoff[part][l16];
            float Sr = eo.x + (Mpr*Hp.x - Mpi*Hp.y);
            float Si = eo.y + (Mpr*Hp.y + Mpi*Hp.x);
            float wr = rr*Sr - ri*Si;      // w = r * S
            float wi = rr*Si + ri*Sr;
            float* yp = ych + (size_t)(k*CL + part*PLEN)*DD + l16;
#pragma unroll
            for (int t = 0; t < PLEN; ++t) {
                yp[(size_t)t*DD] = hRr[t] + wr;   // plain store: L2 line-merge
                float nwr = rr*wr - ri*wi;        // w *= r
                wi = rr*wi + ri*wr;
                wr = nwr;
            }
        }

        // ---- counted wait: stage(k+1) [8 oldest] done; 32 y-stores fly ----
        if (k + 1 < NITER) {
            asm volatile("s_waitcnt vmcnt(32)" ::: "memory");
            __builtin_amdgcn_s_barrier();                // B1: tile[nxt] ready
            __builtin_amdgcn_sched_barrier(0);
        }
    }
}

extern "C" void kernel_launch(void* const* d_in, const int* in_sizes, int n_in,
                              void* d_out, int out_size, void* d_ws, size_t ws_size,
                              hipStream_t stream) {
    const float* x     = (const float*)d_in[0];
    const float* decay = (const float*)d_in[1];
    const float* freq  = (const float*)d_in[2];
    float*       y     = (float*)d_out;

    // single dispatch; no workspace, no flags, no memset
    fftconv_persist<<<NCHAIN, NTHR, 0, stream>>>(x, decay, freq, y);
}